// Round 4
// baseline (154.365 us; speedup 1.0000x reference)
//
#include <hip/hip_runtime.h>
#include <hip/hip_cooperative_groups.h>

// v10: single cooperative dispatch (proj + grid.sync + reduce).
// v9 post-mortem: removing half the LDS traffic REGRESSED 11 us -- exactly the
// cost of one extra dependent dispatch (k_prep ~1.5 us of work). Combined with
// v8's neutral reorder, the model is: k_proj ~10 us (pipe floor), k_reduce
// ~4 us, fill 43 us (harness), and ~30 us of per-dispatch gaps. Dispatch count
// is the controllable term. v10 reverts to v8's k_proj body (params in LDS)
// and fuses the reduction behind cg::this_grid().sync(): grid = NS*B = 512
// blocks, 64 KB LDS -> exactly 2 blocks/CU co-resident (valid cooperative),
// __launch_bounds__(512,4) pins VGPR<=128 so occupancy holds. Fallback to the
// two-kernel v8 path if cooperative launch is unavailable.

#define S 128
#define NS 32            // K-splits: 31 x 640 + 1 x 160 atoms
#define PER 640
#define BLOCK 512        // 8 waves: quad = wav&3, half (K-half of chunk) = wav>>2
#define KC 32            // atoms per chunk (2 MFMA K-steps)
#define GSTR 40          // f16 per position row: 32 atoms + 8 pad (80 B)

namespace cg = cooperative_groups;

typedef _Float16 f16;
typedef _Float16 f16x2 __attribute__((ext_vector_type(2)));
typedef _Float16 f16x8 __attribute__((ext_vector_type(8)));
typedef float floatx16 __attribute__((ext_vector_type(16)));

#if __has_builtin(__builtin_amdgcn_exp2f)
#define FAST_EXP2(x) __builtin_amdgcn_exp2f(x)
#else
#define FAST_EXP2(x) exp2f(x)
#endif
#if __has_builtin(__builtin_amdgcn_rcpf)
#define FAST_RCP(x) __builtin_amdgcn_rcpf(x)
#else
#define FAST_RCP(x) (1.0f / (x))
#endif

static __device__ __forceinline__ f16x2 PKRTZ(float a, float b) {
#if __has_builtin(__builtin_amdgcn_cvt_pkrtz)
    return __builtin_bit_cast(f16x2, __builtin_amdgcn_cvt_pkrtz(a, b));
#else
    return (f16x2){(f16)a, (f16)b};
#endif
}

union frag_u { f16x8 v; f16x2 h[4]; };

union SharedU {
    struct {
        float4 sG[2][PER];           // per-axis params (mu, z, w, pad): 20480 B
        f16 g[2][2][S * GSTR];       // [parity][axis][pos*GSTR + atom]: 40960 B
    } m;
    float red[4 * 4096];             // 64 KB cross-half reduce (epilogue alias)
    float lred[7][64][9];            // reduce-phase wave combine (16128 B)
};

// ---- shared device body: projection into partials ----
template <typename SH>
static __device__ __forceinline__ void proj_body(
    SH& sh, const float* __restrict__ mol, const float* __restrict__ stds,
    const float* __restrict__ dens, f16* __restrict__ part, int B, int A)
{
    const int ks   = blockIdx.x;
    const int b    = blockIdx.y;
    const int tid  = threadIdx.x;
    const int lane = tid & 63;
    const int wav  = tid >> 6;
    const int quad = wav & 3;        // image quadrant (64x64)
    const int half = wav >> 2;       // K-half within chunk (16 atoms)
    const int l31  = lane & 31;
    const int hi   = lane >> 5;

    const int a0  = ks * PER;
    const int a1  = min(a0 + PER, A);
    const int cnt = a1 - a0;          // 640 or 160, both divisible by KC

    for (int i = tid; i < cnt; i += BLOCK) {
        const int a = a0 + i;
        const size_t idx = (size_t)b * A + a;
        float x  = mol[idx * 3 + 0];
        float y  = mol[idx * 3 + 1];
        float v  = stds[a] * stds[a];
        float rv = FAST_RCP(v);
        float z  = -0.72134752044448f * rv;                 // -0.5*log2(e)/var
        float w  = __log2f(dens[a] * 0.15915494309189535f * rv);
        sh.m.sG[0][i] = make_float4(x, z, 0.f, 0.f);        // gx: no coef
        sh.m.sG[1][i] = make_float4(y, z, w,   0.f);        // gy: carries coef
    }
    __syncthreads();

    const int nc = cnt >> 5;          // chunks of 32 atoms: 20 or 5

    // generation role: wave -> (axis, 8-atom group); positions = lane, lane+64
    const int gaxis = wav >> 2;       // 0 = gx (cols), 1 = gy (rows)
    const int agrp  = wav & 3;
    const float c0  = (float)lane - 63.5f;

    // compute role addresses (f16 units)
    const int arow = (quad >> 1) * 64 + l31;
    const int acol = (quad & 1) * 64 + l31;
    const int aoff = half * 16 + hi * 8;   // k = chunk-atom: elem j -> aoff+j

    floatx16 acc[2][2];
#pragma unroll
    for (int rr = 0; rr < 2; ++rr)
#pragma unroll
        for (int cb = 0; cb < 2; ++cb) acc[rr][cb] = (floatx16){0.f};

    // compute chunk c's fragment values into regs (param reads issue first)
    auto GEN_COMPUTE = [&](int c, frag_u& V0, frag_u& V1) {
        const float4* prm = &sh.m.sG[gaxis][c * KC + agrp * 8];  // wave-uniform
#pragma unroll
        for (int i2 = 0; i2 < 4; ++i2) {
            float e0[2], e1[2];
#pragma unroll
            for (int u = 0; u < 2; ++u) {
                float4 p = prm[i2 * 2 + u];      // (mu, z, w)
                float d  = c0 - p.x;
                float t  = p.y * d;
                float g0 = fmaf(t, d, p.z);
                float g1 = fmaf(128.0f, t, fmaf(4096.0f, p.y, g0));  // pos +64
                e0[u] = FAST_EXP2(g0);
                e1[u] = FAST_EXP2(g1);
            }
            V0.h[i2] = PKRTZ(e0[0], e0[1]);
            V1.h[i2] = PKRTZ(e1[0], e1[1]);
        }
    };

#define STEP(P)                                                                \
    do {                                                                       \
        const f16* gy = sh.m.g[(P)][1];                                        \
        const f16* gx = sh.m.g[(P)][0];                                        \
        const bool gen = (c + 1 < nc);                                         \
        frag_u V0, V1;                                                         \
        if (gen) GEN_COMPUTE(c + 1, V0, V1);                                   \
        frag_u A0, A1, B0, B1;                                                 \
        A0.v = *(const f16x8*)(gy + arow * GSTR + aoff);                       \
        A1.v = *(const f16x8*)(gy + (arow + 32) * GSTR + aoff);                \
        B0.v = *(const f16x8*)(gx + acol * GSTR + aoff);                       \
        B1.v = *(const f16x8*)(gx + (acol + 32) * GSTR + aoff);                \
        acc[0][0] = __builtin_amdgcn_mfma_f32_32x32x16_f16(A0.v, B0.v, acc[0][0], 0, 0, 0); \
        acc[0][1] = __builtin_amdgcn_mfma_f32_32x32x16_f16(A0.v, B1.v, acc[0][1], 0, 0, 0); \
        acc[1][0] = __builtin_amdgcn_mfma_f32_32x32x16_f16(A1.v, B0.v, acc[1][0], 0, 0, 0); \
        acc[1][1] = __builtin_amdgcn_mfma_f32_32x32x16_f16(A1.v, B1.v, acc[1][1], 0, 0, 0); \
        if (gen) {                                                             \
            f16* dst = &sh.m.g[(P) ^ 1][gaxis][lane * GSTR + agrp * 8];        \
            *(f16x8*)dst               = V0.v;                                 \
            *(f16x8*)(dst + 64 * GSTR) = V1.v;                                 \
        }                                                                      \
        __syncthreads();                                                       \
        ++c;                                                                   \
    } while (0)

    {   // prologue: chunk 0 into parity 0
        frag_u V0, V1;
        GEN_COMPUTE(0, V0, V1);
        f16* dst = &sh.m.g[0][gaxis][lane * GSTR + agrp * 8];
        *(f16x8*)dst               = V0.v;
        *(f16x8*)(dst + 64 * GSTR) = V1.v;
    }
    __syncthreads();

    int c = 0;
    while (c + 2 <= nc) { STEP(0); STEP(1); }
    if (c < nc) STEP(0);              // nc odd (tail split): even parity
#undef STEP

    // cross-half reduce: [j][lane] layout (lane-consecutive -> conflict-free)
    float* rq = sh.red + quad * 4096;
    if (half == 0) {
#pragma unroll
        for (int rr = 0; rr < 2; ++rr)
#pragma unroll
            for (int cb = 0; cb < 2; ++cb) {
                float* t = rq + (rr * 2 + cb) * 1024 + lane;
#pragma unroll
                for (int j = 0; j < 16; ++j) t[j * 64] = acc[rr][cb][j];
            }
    }
    __syncthreads();

    if (half == 1) {
        f16* base = part + ((size_t)(b * NS + ks)) * (S * S) + lane * 16;
#pragma unroll
        for (int rr = 0; rr < 2; ++rr)
#pragma unroll
            for (int cb = 0; cb < 2; ++cb) {
                float* t = rq + (rr * 2 + cb) * 1024 + lane;
                floatx16 v = acc[rr][cb];
#pragma unroll
                for (int j = 0; j < 16; ++j) v[j] += t[j * 64];
                const int tileidx = ((quad >> 1) * 2 + rr) * 4 + ((quad & 1) * 2 + cb);
                f16* pq = base + (size_t)tileidx * 1024;
                frag_u lo, hiv;
#pragma unroll
                for (int jp = 0; jp < 4; ++jp) {
                    lo.h[jp]  = PKRTZ(v[2 * jp],     v[2 * jp + 1]);
                    hiv.h[jp] = PKRTZ(v[2 * jp + 8], v[2 * jp + 9]);
                }
                *(f16x8*)(pq + 0) = lo.v;
                *(f16x8*)(pq + 8) = hiv.v;
            }
    }
}

// ---- fused cooperative kernel: proj -> grid.sync -> reduce ----
__global__ __launch_bounds__(BLOCK, 4) void k_fused(
    const float* __restrict__ mol, const float* __restrict__ stds,
    const float* __restrict__ dens, f16* __restrict__ part,
    float* __restrict__ out, int B, int A)
{
    __shared__ SharedU sh;
    proj_body(sh, mol, stds, dens, part, B, A);

    cg::this_grid().sync();   // all partials visible; also a block barrier

    // reduce phase: 512 blocks re-map; block rb handles 64 f8-groups of image rbb
    const int tid  = threadIdx.x;
    const int lane = tid & 63;
    const int wav  = tid >> 6;
    const int rb   = blockIdx.y * NS + blockIdx.x;
    const int rbx  = rb & 31;
    const int rbb  = rb >> 5;
    const int f8   = (rbx * 64 + lane) * 8;   // frag-order base idx

    const f16* src = part + (size_t)rbb * NS * (S * S) + (size_t)(wav * 4) * (S * S) + f8;
    float s[8] = {0.f};
#pragma unroll
    for (int t = 0; t < 4; ++t) {
        f16x8 v = *(const f16x8*)&src[(size_t)t * (S * S)];
#pragma unroll
        for (int i = 0; i < 8; ++i) s[i] += (float)v[i];
    }

    if (wav) {
#pragma unroll
        for (int i = 0; i < 8; ++i) sh.lred[wav - 1][lane][i] = s[i];
    }
    __syncthreads();

    if (wav == 0) {
#pragma unroll
        for (int j = 0; j < 7; ++j)
#pragma unroll
            for (int i = 0; i < 8; ++i) s[i] += sh.lred[j][lane][i];

        const int reg0   = f8 & 15;
        const int lane_f = (f8 >> 4) & 63;
        const int tile   = f8 >> 10;
        const int r      = tile >> 2;
        const int cc     = tile & 3;
        // mfma_32x32 C/D: col = lane&31, row = (reg&3) + 8*(reg>>2) + 4*(lane>>5)
        const int rowb = r * 32 + 4 * (lane_f >> 5);
        const int col  = cc * 32 + (lane_f & 31);
#pragma unroll
        for (int i = 0; i < 8; ++i) {
            const int reg = reg0 + i;
            const int row = rowb + (reg & 3) + 8 * (reg >> 2);
            out[((size_t)rbb * S + row) * S + col] = s[i];
        }
    }
}

// ---- fallback two-kernel path (v8, known-good) ----
__global__ __launch_bounds__(BLOCK, 4) void k_proj(
    const float* __restrict__ mol, const float* __restrict__ stds,
    const float* __restrict__ dens, f16* __restrict__ part, int B, int A)
{
    __shared__ SharedU sh;
    proj_body(sh, mol, stds, dens, part, B, A);
}

__global__ __launch_bounds__(256) void k_reduce(const f16* __restrict__ part,
                                                float* __restrict__ out) {
    __shared__ float lred[3][64][9];
    const int b    = blockIdx.z;
    const int lane = threadIdx.x & 63;
    const int w    = threadIdx.x >> 6;
    const int f8   = (blockIdx.x * 64 + lane) * 8;

    const f16* src = part + (size_t)b * NS * (S * S) + (size_t)(w * 8) * (S * S) + f8;
    float s[8] = {0.f};
#pragma unroll
    for (int t = 0; t < 8; ++t) {
        f16x8 v = *(const f16x8*)&src[(size_t)t * (S * S)];
#pragma unroll
        for (int i = 0; i < 8; ++i) s[i] += (float)v[i];
    }

    if (w) {
#pragma unroll
        for (int i = 0; i < 8; ++i) lred[w - 1][lane][i] = s[i];
    }
    __syncthreads();

    if (w == 0) {
#pragma unroll
        for (int j = 0; j < 3; ++j)
#pragma unroll
            for (int i = 0; i < 8; ++i) s[i] += lred[j][lane][i];

        const int reg0   = f8 & 15;
        const int lane_f = (f8 >> 4) & 63;
        const int tile   = f8 >> 10;
        const int r      = tile >> 2;
        const int cc     = tile & 3;
        const int rowb = r * 32 + 4 * (lane_f >> 5);
        const int col  = cc * 32 + (lane_f & 31);
#pragma unroll
        for (int i = 0; i < 8; ++i) {
            const int reg = reg0 + i;
            const int row = rowb + (reg & 3) + 8 * (reg >> 2);
            out[((size_t)b * S + row) * S + col] = s[i];
        }
    }
}

extern "C" void kernel_launch(void* const* d_in, const int* in_sizes, int n_in,
                              void* d_out, int out_size, void* d_ws, size_t ws_size,
                              hipStream_t stream) {
    const float* mol  = (const float*)d_in[0];
    const float* stds = (const float*)d_in[1];
    const float* dens = (const float*)d_in[2];
    float* out = (float*)d_out;

    int A = in_sizes[1];               // 20000
    int B = in_sizes[0] / (A * 3);     // 16

    f16* part = (f16*)d_ws;            // B*NS*16384*2 = 16 MB

    void* args[] = {(void*)&mol, (void*)&stds, (void*)&dens,
                    (void*)&part, (void*)&out, (void*)&B, (void*)&A};
    hipError_t e = hipLaunchCooperativeKernel((const void*)k_fused,
                                              dim3(NS, B), dim3(BLOCK),
                                              args, 0, stream);
    if (e != hipSuccess) {
        (void)hipGetLastError();       // clear; fall back to two-dispatch path
        k_proj<<<dim3(NS, B), dim3(BLOCK), 0, stream>>>(mol, stds, dens, part, B, A);
        k_reduce<<<dim3((S * S) / (64 * 8), 1, B), dim3(256), 0, stream>>>(part, out);
    }
}

// Round 5
// 88.654 us; speedup vs baseline: 1.7412x; 1.7412x over previous
//
#include <hip/hip_runtime.h>

// v11: 2 chunks (64 atoms) per barrier.
// v10 post-mortem: k_fused measured directly at 79 us (MfmaUtil 4.9%, VALU
// 15%) -> proj body ~41 us, grid.sync ~30 us (revert cooperative). v8 budget
// closes exactly: 88.5 = fill 43 + proj 41 + reduce 4, zero dispatch gaps.
// proj is ~60% stall bubbles (issue floor ~10 us, LDS pipe ~14, trans 4,
// MFMA 4); occupancy capped at 4 waves/SIMD by the 64-float acc, so the lever
// is fewer/bigger barrier-free regions: 21 barriers x ~300 cyc of independent
// work -> 11 barriers x 2x work. Parity buffers hold 64 atoms (GSTR=68, pad
// 4); 136 B row stride leaves odd rows 8B-aligned -> all frag/GEN LDS ops are
// b64 pairs (banks ~2-way = free per m136). Single sG[640] float4 (axis
// select in GEN) halves param broadcasts. LDS 78 KB -> still 2 blocks/CU.

#define S 128
#define NS 32            // K-splits: 31 x 640 + 1 x 160 atoms
#define PER 640
#define BLOCK 512        // 8 waves: quad = wav&3, half (K-half of chunk) = wav>>2
#define KC 32            // atoms per chunk (2 MFMA K-steps); 2 chunks per barrier
#define GSTR 68          // f16 per position row: 64 atoms + 4 pad (136 B)

typedef _Float16 f16;
typedef _Float16 f16x2 __attribute__((ext_vector_type(2)));
typedef _Float16 f16x4 __attribute__((ext_vector_type(4)));
typedef _Float16 f16x8 __attribute__((ext_vector_type(8)));
typedef float floatx16 __attribute__((ext_vector_type(16)));

#if __has_builtin(__builtin_amdgcn_exp2f)
#define FAST_EXP2(x) __builtin_amdgcn_exp2f(x)
#else
#define FAST_EXP2(x) exp2f(x)
#endif
#if __has_builtin(__builtin_amdgcn_rcpf)
#define FAST_RCP(x) __builtin_amdgcn_rcpf(x)
#else
#define FAST_RCP(x) (1.0f / (x))
#endif

static __device__ __forceinline__ f16x2 PKRTZ(float a, float b) {
#if __has_builtin(__builtin_amdgcn_cvt_pkrtz)
    return __builtin_bit_cast(f16x2, __builtin_amdgcn_cvt_pkrtz(a, b));
#else
    return (f16x2){(f16)a, (f16)b};
#endif
}

union frag_u { f16x8 v; f16x4 q[2]; f16x2 h[4]; };

union SharedU {
    struct {
        float4 sG[PER];              // (x, y, z, w): 10,240 B
        f16 g[2][2][S * GSTR];       // [parity][axis][pos*GSTR + atom]: 69,632 B
    } m;
    float red[4 * 4096];             // 64 KB cross-half reduce (epilogue alias)
};

__global__ __launch_bounds__(BLOCK, 4) void k_proj(
    const float* __restrict__ mol,   // (B, A, 3)
    const float* __restrict__ stds,  // (A)
    const float* __restrict__ dens,  // (A)
    f16* __restrict__ part,          // (B*NS, 128*128) f16 partials, frag order
    int B, int A)
{
    __shared__ SharedU sh;

    const int ks   = blockIdx.x;
    const int b    = blockIdx.y;
    const int tid  = threadIdx.x;
    const int lane = tid & 63;
    const int wav  = tid >> 6;
    const int quad = wav & 3;        // image quadrant (64x64)
    const int half = wav >> 2;       // K-half within chunk (16 atoms)
    const int l31  = lane & 31;
    const int hi   = lane >> 5;

    const int a0  = ks * PER;
    const int a1  = min(a0 + PER, A);
    const int cnt = a1 - a0;          // 640 or 160, both divisible by KC

    for (int i = tid; i < cnt; i += BLOCK) {
        const int a = a0 + i;
        const size_t idx = (size_t)b * A + a;
        float x  = mol[idx * 3 + 0];
        float y  = mol[idx * 3 + 1];
        float v  = stds[a] * stds[a];
        float rv = FAST_RCP(v);
        float z  = -0.72134752044448f * rv;                 // -0.5*log2(e)/var
        float w  = __log2f(dens[a] * 0.15915494309189535f * rv);
        sh.m.sG[i] = make_float4(x, y, z, w);
    }
    __syncthreads();

    const int nc = cnt >> 5;          // chunks of 32 atoms: 20 or 5

    // generation role: wave -> (axis, 8-atom group); positions = lane, lane+64
    const int gaxis = wav >> 2;       // 0 = gx (cols), 1 = gy (rows)
    const int agrp  = wav & 3;
    const float c0  = (float)lane - 63.5f;

    // compute role addresses (f16 units)
    const int arow = (quad >> 1) * 64 + l31;
    const int acol = (quad & 1) * 64 + l31;
    const int aoff = half * 16 + hi * 8;   // within-chunk atom: elem j -> aoff+j

    floatx16 acc[2][2];
#pragma unroll
    for (int rr = 0; rr < 2; ++rr)
#pragma unroll
        for (int cb = 0; cb < 2; ++cb) acc[rr][cb] = (floatx16){0.f};

    // generate chunk c (8 atoms for this wave) and write into parity buffer
    auto GEN_CHUNK = [&](int c, int par) {
        const float4* prm = &sh.m.sG[c * KC + agrp * 8];  // wave-uniform bcast
        frag_u V0, V1;
#pragma unroll
        for (int i2 = 0; i2 < 4; ++i2) {
            float e0[2], e1[2];
#pragma unroll
            for (int u = 0; u < 2; ++u) {
                float4 p = prm[i2 * 2 + u];      // (x, y, z, w)
                float mu = gaxis ? p.y : p.x;
                float wc = gaxis ? p.w : 0.0f;   // gx carries no coef
                float d  = c0 - mu;
                float t  = p.z * d;
                float g0 = fmaf(t, d, wc);
                float g1 = fmaf(128.0f, t, fmaf(4096.0f, p.z, g0));  // pos +64
                e0[u] = FAST_EXP2(g0);
                e1[u] = FAST_EXP2(g1);
            }
            V0.h[i2] = PKRTZ(e0[0], e0[1]);
            V1.h[i2] = PKRTZ(e1[0], e1[1]);
        }
        f16* dst = &sh.m.g[par][gaxis][lane * GSTR + (c & 1) * 32 + agrp * 8];
        *(f16x4*)(dst)     = V0.q[0];
        *(f16x4*)(dst + 4) = V0.q[1];
        f16* dst2 = dst + 64 * GSTR;             // pos = lane + 64
        *(f16x4*)(dst2)     = V1.q[0];
        *(f16x4*)(dst2 + 4) = V1.q[1];
    };

    // frag reads + 4 MFMAs for slot q (0/1) of the current parity buffers
#define CHUNK_MFMA(gy, gx, qq)                                                 \
    do {                                                                       \
        frag_u A0, A1, B0, B1;                                                 \
        const f16* ay = (gy) + arow * GSTR + (qq) * 32 + aoff;                 \
        const f16* ax = (gx) + acol * GSTR + (qq) * 32 + aoff;                 \
        A0.q[0] = *(const f16x4*)(ay);                                         \
        A0.q[1] = *(const f16x4*)(ay + 4);                                     \
        A1.q[0] = *(const f16x4*)(ay + 32 * GSTR);                             \
        A1.q[1] = *(const f16x4*)(ay + 32 * GSTR + 4);                         \
        B0.q[0] = *(const f16x4*)(ax);                                         \
        B0.q[1] = *(const f16x4*)(ax + 4);                                     \
        B1.q[0] = *(const f16x4*)(ax + 32 * GSTR);                             \
        B1.q[1] = *(const f16x4*)(ax + 32 * GSTR + 4);                         \
        acc[0][0] = __builtin_amdgcn_mfma_f32_32x32x16_f16(A0.v, B0.v, acc[0][0], 0, 0, 0); \
        acc[0][1] = __builtin_amdgcn_mfma_f32_32x32x16_f16(A0.v, B1.v, acc[0][1], 0, 0, 0); \
        acc[1][0] = __builtin_amdgcn_mfma_f32_32x32x16_f16(A1.v, B0.v, acc[1][0], 0, 0, 0); \
        acc[1][1] = __builtin_amdgcn_mfma_f32_32x32x16_f16(A1.v, B1.v, acc[1][1], 0, 0, 0); \
    } while (0)

    // STEP2: consume chunks c, c+1 from parity PAR; generate c+2, c+3 into
    // PAR^1. One barrier per 2 chunks. Writes to PAR^1 are safe pre-barrier:
    // PAR^1 was fully consumed before the PREVIOUS barrier.
#define STEP2(PAR)                                                             \
    do {                                                                       \
        const f16* gy = sh.m.g[(PAR)][1];                                      \
        const f16* gx = sh.m.g[(PAR)][0];                                      \
        if (c + 2 < nc) GEN_CHUNK(c + 2, (PAR) ^ 1);                           \
        CHUNK_MFMA(gy, gx, 0);                                                 \
        if (c + 3 < nc) GEN_CHUNK(c + 3, (PAR) ^ 1);                           \
        if (c + 1 < nc) CHUNK_MFMA(gy, gx, 1);                                 \
        __syncthreads();                                                       \
        c += 2;                                                                \
    } while (0)

    // prologue: chunks 0,1 into parity 0
    GEN_CHUNK(0, 0);
    if (nc > 1) GEN_CHUNK(1, 0);
    __syncthreads();

    int c = 0;
    for (;;) {
        STEP2(0);
        if (c >= nc) break;
        STEP2(1);
        if (c >= nc) break;
    }
#undef STEP2
#undef CHUNK_MFMA

    // cross-half reduce: [j][lane] layout (lane-consecutive -> conflict-free)
    float* rq = sh.red + quad * 4096;
    if (half == 0) {
#pragma unroll
        for (int rr = 0; rr < 2; ++rr)
#pragma unroll
            for (int cb = 0; cb < 2; ++cb) {
                float* t = rq + (rr * 2 + cb) * 1024 + lane;
#pragma unroll
                for (int j = 0; j < 16; ++j) t[j * 64] = acc[rr][cb][j];
            }
    }
    __syncthreads();

    if (half == 1) {
        f16* base = part + ((size_t)(b * NS + ks)) * (S * S) + lane * 16;
#pragma unroll
        for (int rr = 0; rr < 2; ++rr)
#pragma unroll
            for (int cb = 0; cb < 2; ++cb) {
                float* t = rq + (rr * 2 + cb) * 1024 + lane;
                floatx16 v = acc[rr][cb];
#pragma unroll
                for (int j = 0; j < 16; ++j) v[j] += t[j * 64];
                const int tileidx = ((quad >> 1) * 2 + rr) * 4 + ((quad & 1) * 2 + cb);
                f16* pq = base + (size_t)tileidx * 1024;
                frag_u lo, hiv;
#pragma unroll
                for (int jp = 0; jp < 4; ++jp) {
                    lo.h[jp]  = PKRTZ(v[2 * jp],     v[2 * jp + 1]);
                    hiv.h[jp] = PKRTZ(v[2 * jp + 8], v[2 * jp + 9]);
                }
                *(f16x8*)(pq + 0) = lo.v;
                *(f16x8*)(pq + 8) = hiv.v;
            }
    }
}

// sum NS f16 partials per batch: 4 waves/block each sum 8 slices (512 blocks),
// LDS combine, un-permute fragment order, write f32.
__global__ __launch_bounds__(256) void k_reduce(const f16* __restrict__ part,
                                                float* __restrict__ out) {
    __shared__ float lred[3][64][9];   // +1 pad: conflict-free strided stores
    const int b    = blockIdx.z;
    const int lane = threadIdx.x & 63;
    const int w    = threadIdx.x >> 6;
    const int f8   = (blockIdx.x * 64 + lane) * 8;   // frag-order base idx

    const f16* src = part + (size_t)b * NS * (S * S) + (size_t)(w * 8) * (S * S) + f8;
    float s[8] = {0.f};
#pragma unroll
    for (int t = 0; t < 8; ++t) {
        f16x8 v = *(const f16x8*)&src[(size_t)t * (S * S)];
#pragma unroll
        for (int i = 0; i < 8; ++i) s[i] += (float)v[i];
    }

    if (w) {
#pragma unroll
        for (int i = 0; i < 8; ++i) lred[w - 1][lane][i] = s[i];
    }
    __syncthreads();

    if (w == 0) {
#pragma unroll
        for (int j = 0; j < 3; ++j)
#pragma unroll
            for (int i = 0; i < 8; ++i) s[i] += lred[j][lane][i];

        // decode f8 = tile*1024 + lane_f*16 + reg0; tile = r*4 + c (32x32 tiles)
        const int reg0   = f8 & 15;
        const int lane_f = (f8 >> 4) & 63;
        const int tile   = f8 >> 10;
        const int r      = tile >> 2;
        const int cc     = tile & 3;
        // mfma_32x32 C/D: col = lane&31, row = (reg&3) + 8*(reg>>2) + 4*(lane>>5)
        const int rowb = r * 32 + 4 * (lane_f >> 5);
        const int col  = cc * 32 + (lane_f & 31);
#pragma unroll
        for (int i = 0; i < 8; ++i) {
            const int reg = reg0 + i;
            const int row = rowb + (reg & 3) + 8 * (reg >> 2);
            out[((size_t)b * S + row) * S + col] = s[i] ;
        }
    }
}

extern "C" void kernel_launch(void* const* d_in, const int* in_sizes, int n_in,
                              void* d_out, int out_size, void* d_ws, size_t ws_size,
                              hipStream_t stream) {
    const float* mol  = (const float*)d_in[0];
    const float* stds = (const float*)d_in[1];
    const float* dens = (const float*)d_in[2];
    float* out = (float*)d_out;

    const int A = in_sizes[1];             // 20000
    const int B = in_sizes[0] / (A * 3);   // 16

    f16* part = (f16*)d_ws;                // B*NS*16384*2 = 16 MB

    k_proj<<<dim3(NS, B), dim3(BLOCK), 0, stream>>>(mol, stds, dens, part, B, A);
    k_reduce<<<dim3((S * S) / (64 * 8), 1, B), dim3(256), 0, stream>>>(part, out);
}

// Round 6
// 85.853 us; speedup vs baseline: 1.7980x; 1.0326x over previous
//
#include <hip/hip_runtime.h>

// v12: occupancy doubling via tile-per-wave.
// v11 post-mortem: barrier halving neutral. Excluded so far: instr order (v8),
// LDS traffic (v9), barrier count (v11). v10's direct measurement (MfmaUtil
// 4.9%, VALU 15%, Occ 42.7%, all pipes <20%) says k_proj is LATENCY-bound at
// 4 waves/SIMD (acc 64 VGPR + 64 KB LDS cap). Since v7, exp work is fixed by
// the cooperative GEN -- consumer-wave count is free. v12: BLOCK=1024, 16
// waves, each owns ONE 32x32 tile (acc = f32x16 = 16 regs) over full K ->
// no cross-half reduce (red[] deleted, 2 barriers saved, direct store).
// GEN: wave = (axis, 4-atom group), 8 exps/lane/chunk (was 16). LDS 51.2 KB,
// 2 blocks x 16 waves = 32 waves/CU = 8/SIMD (100%). launch_bounds(1024,8)
// pins VGPR <= 64.

#define S 128
#define NS 32            // K-splits: 31 x 640 + 1 x 160 atoms
#define PER 640
#define BLOCK 1024       // 16 waves: tile = wav (r=wav>>2, c=wav&3)
#define KC 32            // atoms per chunk (2 MFMA K-steps)
#define GSTR 40          // f16 per position row: 32 atoms + 8 pad (80 B)

typedef _Float16 f16;
typedef _Float16 f16x2 __attribute__((ext_vector_type(2)));
typedef _Float16 f16x4 __attribute__((ext_vector_type(4)));
typedef _Float16 f16x8 __attribute__((ext_vector_type(8)));
typedef float floatx16 __attribute__((ext_vector_type(16)));

#if __has_builtin(__builtin_amdgcn_exp2f)
#define FAST_EXP2(x) __builtin_amdgcn_exp2f(x)
#else
#define FAST_EXP2(x) exp2f(x)
#endif
#if __has_builtin(__builtin_amdgcn_rcpf)
#define FAST_RCP(x) __builtin_amdgcn_rcpf(x)
#else
#define FAST_RCP(x) (1.0f / (x))
#endif

static __device__ __forceinline__ f16x2 PKRTZ(float a, float b) {
#if __has_builtin(__builtin_amdgcn_cvt_pkrtz)
    return __builtin_bit_cast(f16x2, __builtin_amdgcn_cvt_pkrtz(a, b));
#else
    return (f16x2){(f16)a, (f16)b};
#endif
}

union frag_u { f16x8 v; f16x4 q[2]; f16x2 h[4]; };
union half4_u { f16x4 q; f16x2 h[2]; };

struct SharedT {
    float4 sG[PER];              // (x, y, z, w): 10,240 B
    f16 g[2][2][S * GSTR];       // [parity][axis][pos*GSTR + atom]: 40,960 B
};                               // 51,200 B -> 2 blocks/CU, 32 waves/CU

__global__ __launch_bounds__(BLOCK, 8) void k_proj(
    const float* __restrict__ mol,   // (B, A, 3)
    const float* __restrict__ stds,  // (A)
    const float* __restrict__ dens,  // (A)
    f16* __restrict__ part,          // (B*NS, 128*128) f16 partials, frag order
    int B, int A)
{
    __shared__ SharedT sh;

    const int ks   = blockIdx.x;
    const int b    = blockIdx.y;
    const int tid  = threadIdx.x;
    const int lane = tid & 63;
    const int wav  = tid >> 6;       // 0..15 = output tile index (r*4 + c)
    const int l31  = lane & 31;
    const int hi   = lane >> 5;

    const int a0  = ks * PER;
    const int a1  = min(a0 + PER, A);
    const int cnt = a1 - a0;          // 640 or 160, both divisible by KC

    for (int i = tid; i < cnt; i += BLOCK) {
        const int a = a0 + i;
        const size_t idx = (size_t)b * A + a;
        float x  = mol[idx * 3 + 0];
        float y  = mol[idx * 3 + 1];
        float v  = stds[a] * stds[a];
        float rv = FAST_RCP(v);
        float z  = -0.72134752044448f * rv;                 // -0.5*log2(e)/var
        float w  = __log2f(dens[a] * 0.15915494309189535f * rv);
        sh.sG[i] = make_float4(x, y, z, w);
    }
    __syncthreads();

    const int nc = cnt >> 5;          // chunks of 32 atoms: 20 or 5

    // GEN role: wave -> (axis, 4-atom group); positions = lane, lane+64
    const int gaxis = wav >> 3;       // 0 = gx (cols), 1 = gy (rows)
    const int agrp  = wav & 7;        // 8 groups x 4 atoms = 32 atoms
    const float c0  = (float)lane - 63.5f;

    // compute role: tile (r = wav>>2, c = wav&3); frag rows/cols per lane
    const int arow = (wav >> 2) * 32 + l31;   // gy row
    const int bcol = (wav & 3) * 32 + l31;    // gx col
    const int koff = hi * 8;                  // K-step atom sub-offset

    floatx16 acc = (floatx16){0.f};

    // compute chunk c's 8 values (4 atoms x 2 positions) into regs
    auto GEN_COMPUTE = [&](int c, half4_u& V0, half4_u& V1) {
        const float4* prm = &sh.sG[c * KC + agrp * 4];   // wave-uniform bcast
#pragma unroll
        for (int i2 = 0; i2 < 2; ++i2) {
            float e0[2], e1[2];
#pragma unroll
            for (int u = 0; u < 2; ++u) {
                float4 p = prm[i2 * 2 + u];      // (x, y, z, w)
                float mu = gaxis ? p.y : p.x;
                float wc = gaxis ? p.w : 0.0f;   // gx carries no coef
                float d  = c0 - mu;
                float t  = p.z * d;
                float g0 = fmaf(t, d, wc);
                float g1 = fmaf(128.0f, t, fmaf(4096.0f, p.z, g0));  // pos +64
                e0[u] = FAST_EXP2(g0);
                e1[u] = FAST_EXP2(g1);
            }
            V0.h[i2] = PKRTZ(e0[0], e0[1]);
            V1.h[i2] = PKRTZ(e1[0], e1[1]);
        }
    };

    // STEP: consume chunk c from parity P; generate chunk c+1 into P^1.
    // P^1 was fully consumed before the previous barrier -> safe pre-barrier.
#define STEP(P)                                                                \
    do {                                                                       \
        const f16* gy = sh.g[(P)][1];                                          \
        const f16* gx = sh.g[(P)][0];                                          \
        const bool gen = (c + 1 < nc);                                         \
        half4_u V0, V1;                                                        \
        if (gen) GEN_COMPUTE(c + 1, V0, V1);                                   \
        _Pragma("unroll")                                                      \
        for (int s = 0; s < 2; ++s) {                                          \
            frag_u Af, Bf;                                                     \
            Af.v = *(const f16x8*)(gy + arow * GSTR + s * 16 + koff);          \
            Bf.v = *(const f16x8*)(gx + bcol * GSTR + s * 16 + koff);          \
            acc = __builtin_amdgcn_mfma_f32_32x32x16_f16(Af.v, Bf.v, acc, 0, 0, 0); \
        }                                                                      \
        if (gen) {                                                             \
            f16* dst = &sh.g[(P) ^ 1][gaxis][lane * GSTR + agrp * 4];          \
            *(f16x4*)dst               = V0.q;                                 \
            *(f16x4*)(dst + 64 * GSTR) = V1.q;                                 \
        }                                                                      \
        __syncthreads();                                                       \
        ++c;                                                                   \
    } while (0)

    {   // prologue: chunk 0 into parity 0
        half4_u V0, V1;
        GEN_COMPUTE(0, V0, V1);
        f16* dst = &sh.g[0][gaxis][lane * GSTR + agrp * 4];
        *(f16x4*)dst               = V0.q;
        *(f16x4*)(dst + 64 * GSTR) = V1.q;
    }
    __syncthreads();

    int c = 0;
    while (c + 2 <= nc) { STEP(0); STEP(1); }
    if (c < nc) STEP(0);              // nc odd (tail split): even parity
#undef STEP

    // epilogue: direct store -- wave owns tile wav completely (full K summed)
    {
        f16* pq = part + ((size_t)(b * NS + ks)) * (S * S)
                       + (size_t)wav * 1024 + lane * 16;
        frag_u lo, hiv;
#pragma unroll
        for (int jp = 0; jp < 4; ++jp) {
            lo.h[jp]  = PKRTZ(acc[2 * jp],     acc[2 * jp + 1]);
            hiv.h[jp] = PKRTZ(acc[2 * jp + 8], acc[2 * jp + 9]);
        }
        *(f16x8*)(pq + 0) = lo.v;
        *(f16x8*)(pq + 8) = hiv.v;
    }
}

// sum NS f16 partials per batch: 4 waves/block each sum 8 slices (512 blocks),
// LDS combine, un-permute fragment order, write f32.
__global__ __launch_bounds__(256) void k_reduce(const f16* __restrict__ part,
                                                float* __restrict__ out) {
    __shared__ float lred[3][64][9];   // +1 pad: conflict-free strided stores
    const int b    = blockIdx.z;
    const int lane = threadIdx.x & 63;
    const int w    = threadIdx.x >> 6;
    const int f8   = (blockIdx.x * 64 + lane) * 8;   // frag-order base idx

    const f16* src = part + (size_t)b * NS * (S * S) + (size_t)(w * 8) * (S * S) + f8;
    float s[8] = {0.f};
#pragma unroll
    for (int t = 0; t < 8; ++t) {
        f16x8 v = *(const f16x8*)&src[(size_t)t * (S * S)];
#pragma unroll
        for (int i = 0; i < 8; ++i) s[i] += (float)v[i];
    }

    if (w) {
#pragma unroll
        for (int i = 0; i < 8; ++i) lred[w - 1][lane][i] = s[i];
    }
    __syncthreads();

    if (w == 0) {
#pragma unroll
        for (int j = 0; j < 3; ++j)
#pragma unroll
            for (int i = 0; i < 8; ++i) s[i] += lred[j][lane][i];

        // decode f8 = tile*1024 + lane_f*16 + reg0; tile = r*4 + c (32x32 tiles)
        const int reg0   = f8 & 15;
        const int lane_f = (f8 >> 4) & 63;
        const int tile   = f8 >> 10;
        const int r      = tile >> 2;
        const int cc     = tile & 3;
        // mfma_32x32 C/D: col = lane&31, row = (reg&3) + 8*(reg>>2) + 4*(lane>>5)
        const int rowb = r * 32 + 4 * (lane_f >> 5);
        const int col  = cc * 32 + (lane_f & 31);
#pragma unroll
        for (int i = 0; i < 8; ++i) {
            const int reg = reg0 + i;
            const int row = rowb + (reg & 3) + 8 * (reg >> 2);
            out[((size_t)b * S + row) * S + col] = s[i];
        }
    }
}

extern "C" void kernel_launch(void* const* d_in, const int* in_sizes, int n_in,
                              void* d_out, int out_size, void* d_ws, size_t ws_size,
                              hipStream_t stream) {
    const float* mol  = (const float*)d_in[0];
    const float* stds = (const float*)d_in[1];
    const float* dens = (const float*)d_in[2];
    float* out = (float*)d_out;

    const int A = in_sizes[1];             // 20000
    const int B = in_sizes[0] / (A * 3);   // 16

    f16* part = (f16*)d_ws;                // B*NS*16384*2 = 16 MB

    k_proj<<<dim3(NS, B), dim3(BLOCK), 0, stream>>>(mol, stds, dens, part, B, A);
    k_reduce<<<dim3((S * S) / (64 * 8), 1, B), dim3(256), 0, stream>>>(part, out);
}